// Round 1
// baseline (1666.358 us; speedup 1.0000x reference)
//
#include <hip/hip_runtime.h>
#include <math.h>

#define EPSF 1e-5f
#define MAXN 0.95f
#define DD 128

// Entire exp0 -> proj -> (optional log0) chain is a scalar multiple of the row,
// a function of the row norm only.
__device__ __forceinline__ float chain_scale(float nrm, bool log_out) {
    float nc  = fmaxf(nrm, EPSF);
    float f   = tanhf(nc) / nc;          // exp0 factor
    float wn  = f * nrm;                 // ||w|| after exp0
    float p   = (wn > MAXN) ? (MAXN / fmaxf(wn, EPSF)) : 1.f;  // proj factor
    float s   = f * p;
    if (log_out) {
        float n2  = wn * p;              // norm after proj
        float n2c = fmaxf(n2, EPSF);
        float arg = fminf(n2c, 1.f - EPSF);
        s *= atanhf(arg) / n2c;          // log0 factor
    }
    return s;
}

// out = chain( (LOG_IN ? log0(in) : in) @ W^T + b ), per 64-node tile.
// LOG_OUT: also apply log0 at the end (feeds aggregation or next layer GEMM).
template<int LOG_IN, int LOG_OUT>
__global__ __launch_bounds__(256)
void fused_linear(const float* __restrict__ in, const float* __restrict__ W,
                  const float* __restrict__ bias, float* __restrict__ out, int N)
{
    __shared__ float sWt[DD][DD + 4];   // W transposed: sWt[k][j] = W[j][k]
    __shared__ float sV[64][DD + 4];    // input tile (tangent vectors)

    const int tid = threadIdx.x;
    const int nb  = blockIdx.x * 64;

    // ---- stage W^T into LDS (thread: row j = tid/2, k-half = (tid&1)*64) ----
    {
        const int j  = tid >> 1;
        const int kh = (tid & 1) << 6;
        const float4* wrow = (const float4*)(W + j * DD + kh);
        #pragma unroll
        for (int i = 0; i < 16; ++i) {
            float4 w4 = wrow[i];
            int k = kh + i * 4;
            sWt[k + 0][j] = w4.x;  sWt[k + 1][j] = w4.y;
            sWt[k + 2][j] = w4.z;  sWt[k + 3][j] = w4.w;
        }
    }
    // ---- stage input rows (4 threads per node), optional log0 scale ----
    {
        const int n = tid >> 2, q = tid & 3;
        const int row = nb + n;
        float4 r[8];
        float ss = 0.f;
        if (row < N) {
            const float4* xr = (const float4*)(in + (size_t)row * DD + q * 32);
            #pragma unroll
            for (int i = 0; i < 8; ++i) {
                r[i] = xr[i];
                ss += r[i].x * r[i].x + r[i].y * r[i].y
                    + r[i].z * r[i].z + r[i].w * r[i].w;
            }
        } else {
            #pragma unroll
            for (int i = 0; i < 8; ++i) r[i] = make_float4(0.f, 0.f, 0.f, 0.f);
        }
        float sc = 1.f;
        if (LOG_IN) {
            ss += __shfl_xor(ss, 1);
            ss += __shfl_xor(ss, 2);
            float nrm = sqrtf(ss);
            float nc  = fmaxf(nrm, EPSF);
            float arg = fminf(nc, 1.f - EPSF);
            sc = atanhf(arg) / nc;
        }
        float* vr = &sV[n][q * 32];
        #pragma unroll
        for (int i = 0; i < 8; ++i) {
            *(float4*)(vr + i * 4) =
                make_float4(r[i].x * sc, r[i].y * sc, r[i].z * sc, r[i].w * sc);
        }
    }
    __syncthreads();

    // ---- GEMM: each thread computes 8 nodes x 4 outputs ----
    const int tj = tid & 31, tn = tid >> 5;
    const int j0 = tj * 4,   n0 = tn * 8;
    float4 b4 = *(const float4*)(bias + j0);
    float acc[8][4] = {};
    #pragma unroll 2
    for (int k = 0; k < DD; k += 4) {
        float4 w0 = *(const float4*)(&sWt[k + 0][j0]);
        float4 w1 = *(const float4*)(&sWt[k + 1][j0]);
        float4 w2 = *(const float4*)(&sWt[k + 2][j0]);
        float4 w3 = *(const float4*)(&sWt[k + 3][j0]);
        #pragma unroll
        for (int i = 0; i < 8; ++i) {
            float4 v4 = *(const float4*)(&sV[n0 + i][k]);
            acc[i][0] = fmaf(v4.x, w0.x, fmaf(v4.y, w1.x, fmaf(v4.z, w2.x, fmaf(v4.w, w3.x, acc[i][0]))));
            acc[i][1] = fmaf(v4.x, w0.y, fmaf(v4.y, w1.y, fmaf(v4.z, w2.y, fmaf(v4.w, w3.y, acc[i][1]))));
            acc[i][2] = fmaf(v4.x, w0.z, fmaf(v4.y, w1.z, fmaf(v4.z, w2.z, fmaf(v4.w, w3.z, acc[i][2]))));
            acc[i][3] = fmaf(v4.x, w0.w, fmaf(v4.y, w1.w, fmaf(v4.z, w2.w, fmaf(v4.w, w3.w, acc[i][3]))));
        }
    }
    __syncthreads();
    // ---- write y = acc + b back into sV for per-row norm ----
    #pragma unroll
    for (int i = 0; i < 8; ++i) {
        *(float4*)(&sV[n0 + i][j0]) =
            make_float4(acc[i][0] + b4.x, acc[i][1] + b4.y,
                        acc[i][2] + b4.z, acc[i][3] + b4.w);
    }
    __syncthreads();
    // ---- epilogue: row norm -> chain scale -> store ----
    {
        const int n = tid >> 2, q = tid & 3;
        const int row = nb + n;
        float4 y[8];
        float ss = 0.f;
        const float* vr = &sV[n][q * 32];
        #pragma unroll
        for (int i = 0; i < 8; ++i) {
            y[i] = *(const float4*)(vr + i * 4);
            ss += y[i].x * y[i].x + y[i].y * y[i].y
                + y[i].z * y[i].z + y[i].w * y[i].w;
        }
        ss += __shfl_xor(ss, 1);
        ss += __shfl_xor(ss, 2);
        float s = chain_scale(sqrtf(ss), LOG_OUT != 0);
        if (row < N) {
            float4* orow = (float4*)(out + (size_t)row * DD + q * 32);
            #pragma unroll
            for (int i = 0; i < 8; ++i)
                orow[i] = make_float4(y[i].x * s, y[i].y * s, y[i].z * s, y[i].w * s);
        }
    }
}

// One wave per edge: sum[dst] += g[src]  (g already = log0(h)), cnt[dst] += 1.
__global__ __launch_bounds__(256)
void edge_scatter(const float* __restrict__ g, const int* __restrict__ src,
                  const int* __restrict__ dst, float* __restrict__ sum,
                  float* __restrict__ cnt, int E)
{
    int w = blockIdx.x * 4 + (threadIdx.x >> 6);
    if (w >= E) return;
    int lane = threadIdx.x & 63;
    int s = src[w], d = dst[w];
    float2 v = *(const float2*)(g + (size_t)s * DD + lane * 2);
    atomicAdd(&sum[(size_t)d * DD + lane * 2 + 0], v.x);
    atomicAdd(&sum[(size_t)d * DD + lane * 2 + 1], v.y);
    if (lane == 0) atomicAdd(&cnt[d], 1.f);
}

// In-place: sum[n] := log0(proj(exp0(sum[n] / max(cnt[n],1))))
__global__ __launch_bounds__(256)
void finalize_agg(float* __restrict__ sum, const float* __restrict__ cnt, int N)
{
    int n = blockIdx.x * 64 + (threadIdx.x >> 2);
    int q = threadIdx.x & 3;
    if (n >= N) return;
    float inv = 1.f / fmaxf(cnt[n], 1.f);
    float4* sr = (float4*)(sum + (size_t)n * DD + q * 32);
    float4 m[8];
    float ss = 0.f;
    #pragma unroll
    for (int i = 0; i < 8; ++i) {
        float4 t = sr[i];
        m[i] = make_float4(t.x * inv, t.y * inv, t.z * inv, t.w * inv);
        ss += m[i].x * m[i].x + m[i].y * m[i].y + m[i].z * m[i].z + m[i].w * m[i].w;
    }
    ss += __shfl_xor(ss, 1);
    ss += __shfl_xor(ss, 2);
    float s = chain_scale(sqrtf(ss), true);
    #pragma unroll
    for (int i = 0; i < 8; ++i)
        sr[i] = make_float4(m[i].x * s, m[i].y * s, m[i].z * s, m[i].w * s);
}

extern "C" void kernel_launch(void* const* d_in, const int* in_sizes, int n_in,
                              void* d_out, int out_size, void* d_ws, size_t ws_size,
                              hipStream_t stream)
{
    const float* x     = (const float*)d_in[0];
    const int*   ei    = (const int*)d_in[1];
    const float* msg_W = (const float*)d_in[2];
    const float* msg_b = (const float*)d_in[3];
    const float* upd_W = (const float*)d_in[4];
    const float* upd_b = (const float*)d_in[5];

    const int N = in_sizes[0] / DD;
    const int E = in_sizes[1] / 2;
    const int L = in_sizes[2] / (DD * DD);

    const int* src = ei;
    const int* dst = ei + E;

    float* bufA = (float*)d_ws;                 // N*DD scratch
    float* cnt  = bufA + (size_t)N * DD;        // N counters
    float* outp = (float*)d_out;

    const int nodeBlocks = (N + 63) / 64;
    const int edgeBlocks = (E + 3) / 4;

    for (int l = 0; l < L; ++l) {
        const float* Wm = msg_W + (size_t)l * DD * DD;
        const float* bm = msg_b + (size_t)l * DD;
        const float* Wu = upd_W + (size_t)l * DD * DD;
        const float* bu = upd_b + (size_t)l * DD;

        float* P = (l % 2 == 0) ? bufA : outp;  // g buffer, then K5 dest
        float* Q = (l % 2 == 0) ? outp : bufA;  // sum buffer / K5 source
        const float* lin = (l == 0) ? x : Q;    // prev layer's K5 wrote current Q

        // K1: g = log0(proj(exp0( (log0?)(in) @ Wm^T + bm )))
        if (l == 0)
            fused_linear<1, 1><<<nodeBlocks, 256, 0, stream>>>(lin, Wm, bm, P, N);
        else
            fused_linear<0, 1><<<nodeBlocks, 256, 0, stream>>>(lin, Wm, bm, P, N);

        // K2: zero accumulators
        hipMemsetAsync(Q,   0, (size_t)N * DD * sizeof(float), stream);
        hipMemsetAsync(cnt, 0, (size_t)N * sizeof(float),      stream);

        // K3: scatter-add g[src] into sum[dst]
        edge_scatter<<<edgeBlocks, 256, 0, stream>>>(P, src, dst, Q, cnt, E);

        // K4: in-place mean -> exp0 -> proj -> log0
        finalize_agg<<<nodeBlocks, 256, 0, stream>>>(Q, cnt, N);

        // K5: update linear; last layer emits the actual manifold point
        if (l == L - 1)
            fused_linear<0, 0><<<nodeBlocks, 256, 0, stream>>>(Q, Wu, bu, P, N);
        else
            fused_linear<0, 1><<<nodeBlocks, 256, 0, stream>>>(Q, Wu, bu, P, N);
    }

    if (L % 2 == 1)  // final result would be in bufA; copy out (L=2 -> no-op)
        hipMemcpyAsync(d_out, bufA, (size_t)N * DD * sizeof(float),
                       hipMemcpyDeviceToDevice, stream);
}

// Round 2
// 496.292 us; speedup vs baseline: 3.3576x; 3.3576x over previous
//
#include <hip/hip_runtime.h>
#include <math.h>

#define EPSF 1e-5f
#define MAXN 0.95f
#define DD 128

// Entire exp0 -> proj -> (optional log0) chain is a scalar multiple of the row,
// a function of the row norm only.
__device__ __forceinline__ float chain_scale(float nrm, bool log_out) {
    float nc  = fmaxf(nrm, EPSF);
    float f   = tanhf(nc) / nc;          // exp0 factor
    float wn  = f * nrm;                 // ||w|| after exp0
    float p   = (wn > MAXN) ? (MAXN / fmaxf(wn, EPSF)) : 1.f;  // proj factor
    float s   = f * p;
    if (log_out) {
        float n2  = wn * p;              // norm after proj
        float n2c = fmaxf(n2, EPSF);
        float arg = fminf(n2c, 1.f - EPSF);
        s *= atanhf(arg) / n2c;          // log0 factor
    }
    return s;
}

// out = chain( (LOG_IN ? log0(in) : in) @ W^T + b ), per 64-node tile.
template<int LOG_IN, int LOG_OUT>
__global__ __launch_bounds__(256)
void fused_linear(const float* __restrict__ in, const float* __restrict__ W,
                  const float* __restrict__ bias, float* __restrict__ out, int N)
{
    __shared__ float sWt[DD][DD + 4];   // W transposed: sWt[k][j] = W[j][k]
    __shared__ float sV[64][DD + 4];    // input tile (tangent vectors)

    const int tid = threadIdx.x;
    const int nb  = blockIdx.x * 64;

    // ---- stage W^T into LDS ----
    {
        const int j  = tid >> 1;
        const int kh = (tid & 1) << 6;
        const float4* wrow = (const float4*)(W + j * DD + kh);
        #pragma unroll
        for (int i = 0; i < 16; ++i) {
            float4 w4 = wrow[i];
            int k = kh + i * 4;
            sWt[k + 0][j] = w4.x;  sWt[k + 1][j] = w4.y;
            sWt[k + 2][j] = w4.z;  sWt[k + 3][j] = w4.w;
        }
    }
    // ---- stage input rows (4 threads per node), optional log0 scale ----
    {
        const int n = tid >> 2, q = tid & 3;
        const int row = nb + n;
        float4 r[8];
        float ss = 0.f;
        if (row < N) {
            const float4* xr = (const float4*)(in + (size_t)row * DD + q * 32);
            #pragma unroll
            for (int i = 0; i < 8; ++i) {
                r[i] = xr[i];
                ss += r[i].x * r[i].x + r[i].y * r[i].y
                    + r[i].z * r[i].z + r[i].w * r[i].w;
            }
        } else {
            #pragma unroll
            for (int i = 0; i < 8; ++i) r[i] = make_float4(0.f, 0.f, 0.f, 0.f);
        }
        float sc = 1.f;
        if (LOG_IN) {
            ss += __shfl_xor(ss, 1);
            ss += __shfl_xor(ss, 2);
            float nrm = sqrtf(ss);
            float nc  = fmaxf(nrm, EPSF);
            float arg = fminf(nc, 1.f - EPSF);
            sc = atanhf(arg) / nc;
        }
        float* vr = &sV[n][q * 32];
        #pragma unroll
        for (int i = 0; i < 8; ++i) {
            *(float4*)(vr + i * 4) =
                make_float4(r[i].x * sc, r[i].y * sc, r[i].z * sc, r[i].w * sc);
        }
    }
    __syncthreads();

    // ---- GEMM: each thread computes 8 nodes x 4 outputs ----
    const int tj = tid & 31, tn = tid >> 5;
    const int j0 = tj * 4,   n0 = tn * 8;
    float4 b4 = *(const float4*)(bias + j0);
    float acc[8][4] = {};
    #pragma unroll 2
    for (int k = 0; k < DD; k += 4) {
        float4 w0 = *(const float4*)(&sWt[k + 0][j0]);
        float4 w1 = *(const float4*)(&sWt[k + 1][j0]);
        float4 w2 = *(const float4*)(&sWt[k + 2][j0]);
        float4 w3 = *(const float4*)(&sWt[k + 3][j0]);
        #pragma unroll
        for (int i = 0; i < 8; ++i) {
            float4 v4 = *(const float4*)(&sV[n0 + i][k]);
            acc[i][0] = fmaf(v4.x, w0.x, fmaf(v4.y, w1.x, fmaf(v4.z, w2.x, fmaf(v4.w, w3.x, acc[i][0]))));
            acc[i][1] = fmaf(v4.x, w0.y, fmaf(v4.y, w1.y, fmaf(v4.z, w2.y, fmaf(v4.w, w3.y, acc[i][1]))));
            acc[i][2] = fmaf(v4.x, w0.z, fmaf(v4.y, w1.z, fmaf(v4.z, w2.z, fmaf(v4.w, w3.z, acc[i][2]))));
            acc[i][3] = fmaf(v4.x, w0.w, fmaf(v4.y, w1.w, fmaf(v4.z, w2.w, fmaf(v4.w, w3.w, acc[i][3]))));
        }
    }
    __syncthreads();
    #pragma unroll
    for (int i = 0; i < 8; ++i) {
        *(float4*)(&sV[n0 + i][j0]) =
            make_float4(acc[i][0] + b4.x, acc[i][1] + b4.y,
                        acc[i][2] + b4.z, acc[i][3] + b4.w);
    }
    __syncthreads();
    // ---- epilogue: row norm -> chain scale -> store ----
    {
        const int n = tid >> 2, q = tid & 3;
        const int row = nb + n;
        float4 y[8];
        float ss = 0.f;
        const float* vr = &sV[n][q * 32];
        #pragma unroll
        for (int i = 0; i < 8; ++i) {
            y[i] = *(const float4*)(vr + i * 4);
            ss += y[i].x * y[i].x + y[i].y * y[i].y
                + y[i].z * y[i].z + y[i].w * y[i].w;
        }
        ss += __shfl_xor(ss, 1);
        ss += __shfl_xor(ss, 2);
        float s = chain_scale(sqrtf(ss), LOG_OUT != 0);
        if (row < N) {
            float4* orow = (float4*)(out + (size_t)row * DD + q * 32);
            #pragma unroll
            for (int i = 0; i < 8; ++i)
                orow[i] = make_float4(y[i].x * s, y[i].y * s, y[i].z * s, y[i].w * s);
        }
    }
}

// ---------------- CSR build (once per launch; edge list is layer-invariant) --

__global__ __launch_bounds__(256)
void degree_k(const int* __restrict__ dst, int* __restrict__ deg, int E)
{
    int e = blockIdx.x * 256 + threadIdx.x;
    if (e < E) atomicAdd(&deg[dst[e]], 1);
}

// Single-block exclusive scan: rowptr[0..N], rowptr[N] = E.
__global__ __launch_bounds__(1024)
void scan_rowptr(const int* __restrict__ deg, int* __restrict__ rowptr, int N)
{
    __shared__ int wsum[16];
    const int t = threadIdx.x, wv = t >> 6, ln = t & 63;
    int carry = 0;
    const int nch = (N + 1023) / 1024;
    for (int c = 0; c < nch; ++c) {
        int i = c * 1024 + t;
        int v = (i < N) ? deg[i] : 0;
        // inclusive scan within wave
        int sc = v;
        #pragma unroll
        for (int off = 1; off < 64; off <<= 1) {
            int u = __shfl_up(sc, off);
            if (ln >= off) sc += u;
        }
        if (ln == 63) wsum[wv] = sc;
        __syncthreads();
        if (wv == 0 && ln < 16) {
            int s2 = wsum[ln];
            #pragma unroll
            for (int off = 1; off < 16; off <<= 1) {
                int u = __shfl_up(s2, off);
                if (ln >= off) s2 += u;
            }
            wsum[ln] = s2;   // inclusive wave-total scan
        }
        __syncthreads();
        int woff = (wv > 0) ? wsum[wv - 1] : 0;
        if (i < N) rowptr[i] = carry + woff + sc - v;
        carry += wsum[15];
        __syncthreads();     // protect wsum before next chunk overwrites
    }
    if (t == 0) rowptr[N] = carry;
}

__global__ __launch_bounds__(256)
void fill_csr(const int* __restrict__ src, const int* __restrict__ dst,
              const int* __restrict__ rowptr, int* __restrict__ fill,
              int* __restrict__ csr, int E)
{
    int e = blockIdx.x * 256 + threadIdx.x;
    if (e >= E) return;
    int d = dst[e];
    int pos = rowptr[d] + atomicAdd(&fill[d], 1);
    csr[pos] = src[e];
}

// ---------------- Fused gather-aggregate: one wave per node ------------------
// out[n] = log0(proj(exp0( mean_{e in in(n)} g[src(e)] )))
__global__ __launch_bounds__(256)
void csr_aggregate(const float* __restrict__ g, const int* __restrict__ rowptr,
                   const int* __restrict__ csr, float* __restrict__ out, int N)
{
    int w = blockIdx.x * 4 + (threadIdx.x >> 6);
    if (w >= N) return;
    const int lane = threadIdx.x & 63;
    const int beg = rowptr[w], end = rowptr[w + 1];

    float ax = 0.f, ay = 0.f;
    for (int base = beg; base < end; base += 64) {
        int cnt = min(end - base, 64);
        int myidx = (lane < cnt) ? csr[base + lane] : 0;   // one coalesced load
        for (int j = 0; j < cnt; ++j) {
            int s = __shfl(myidx, j);                      // broadcast edge src
            float2 v = *(const float2*)(g + (size_t)s * DD + lane * 2);
            ax += v.x;  ay += v.y;                         // independent loads
        }
    }
    float inv = 1.f / (float)max(end - beg, 1);
    ax *= inv;  ay *= inv;
    float ss = ax * ax + ay * ay;
    ss += __shfl_xor(ss, 1);  ss += __shfl_xor(ss, 2);
    ss += __shfl_xor(ss, 4);  ss += __shfl_xor(ss, 8);
    ss += __shfl_xor(ss, 16); ss += __shfl_xor(ss, 32);
    float s = chain_scale(sqrtf(ss), true);
    *(float2*)(out + (size_t)w * DD + lane * 2) = make_float2(ax * s, ay * s);
}

// ---------------- Fallback (R1 path) if workspace is too small ---------------
__global__ __launch_bounds__(256)
void edge_scatter(const float* __restrict__ g, const int* __restrict__ src,
                  const int* __restrict__ dst, float* __restrict__ sum,
                  float* __restrict__ cnt, int E)
{
    int w = blockIdx.x * 4 + (threadIdx.x >> 6);
    if (w >= E) return;
    int lane = threadIdx.x & 63;
    int s = src[w], d = dst[w];
    float2 v = *(const float2*)(g + (size_t)s * DD + lane * 2);
    atomicAdd(&sum[(size_t)d * DD + lane * 2 + 0], v.x);
    atomicAdd(&sum[(size_t)d * DD + lane * 2 + 1], v.y);
    if (lane == 0) atomicAdd(&cnt[d], 1.f);
}

__global__ __launch_bounds__(256)
void finalize_agg(float* __restrict__ sum, const float* __restrict__ cnt, int N)
{
    int n = blockIdx.x * 64 + (threadIdx.x >> 2);
    int q = threadIdx.x & 3;
    if (n >= N) return;
    float inv = 1.f / fmaxf(cnt[n], 1.f);
    float4* sr = (float4*)(sum + (size_t)n * DD + q * 32);
    float4 m[8];
    float ss = 0.f;
    #pragma unroll
    for (int i = 0; i < 8; ++i) {
        float4 t = sr[i];
        m[i] = make_float4(t.x * inv, t.y * inv, t.z * inv, t.w * inv);
        ss += m[i].x * m[i].x + m[i].y * m[i].y + m[i].z * m[i].z + m[i].w * m[i].w;
    }
    ss += __shfl_xor(ss, 1);
    ss += __shfl_xor(ss, 2);
    float s = chain_scale(sqrtf(ss), true);
    #pragma unroll
    for (int i = 0; i < 8; ++i)
        sr[i] = make_float4(m[i].x * s, m[i].y * s, m[i].z * s, m[i].w * s);
}

extern "C" void kernel_launch(void* const* d_in, const int* in_sizes, int n_in,
                              void* d_out, int out_size, void* d_ws, size_t ws_size,
                              hipStream_t stream)
{
    const float* x     = (const float*)d_in[0];
    const int*   ei    = (const int*)d_in[1];
    const float* msg_W = (const float*)d_in[2];
    const float* msg_b = (const float*)d_in[3];
    const float* upd_W = (const float*)d_in[4];
    const float* upd_b = (const float*)d_in[5];

    const int N = in_sizes[0] / DD;
    const int E = in_sizes[1] / 2;
    const int L = in_sizes[2] / (DD * DD);

    const int* src = ei;
    const int* dst = ei + E;

    float* bufA   = (float*)d_ws;                       // N*DD scratch
    int*   rowptr = (int*)(bufA + (size_t)N * DD);      // N+1
    int*   deg    = rowptr + (N + 1);                   // N (also fill)
    int*   csr    = deg + N;                            // E
    float* outp   = (float*)d_out;

    const size_t need_csr = (size_t)N * DD * 4 + (size_t)(2 * N + 1 + E) * 4;
    const bool use_csr = ws_size >= need_csr;

    const int nodeBlocks = (N + 63) / 64;
    const int aggBlocks  = (N + 3) / 4;
    const int edgeBlocks = (E + 255) / 256;

    if (use_csr) {
        hipMemsetAsync(deg, 0, (size_t)N * sizeof(int), stream);
        degree_k<<<edgeBlocks, 256, 0, stream>>>(dst, deg, E);
        scan_rowptr<<<1, 1024, 0, stream>>>(deg, rowptr, N);
        hipMemsetAsync(deg, 0, (size_t)N * sizeof(int), stream);
        fill_csr<<<edgeBlocks, 256, 0, stream>>>(src, dst, rowptr, deg, csr, E);
    }

    for (int l = 0; l < L; ++l) {
        const float* Wm = msg_W + (size_t)l * DD * DD;
        const float* bm = msg_b + (size_t)l * DD;
        const float* Wu = upd_W + (size_t)l * DD * DD;
        const float* bu = upd_b + (size_t)l * DD;

        float* P = (l % 2 == 0) ? bufA : outp;
        float* Q = (l % 2 == 0) ? outp : bufA;
        const float* lin = (l == 0) ? x : Q;

        // K1: g = log0(proj(exp0( (log0?)(in) @ Wm^T + bm )))
        if (l == 0)
            fused_linear<1, 1><<<nodeBlocks, 256, 0, stream>>>(lin, Wm, bm, P, N);
        else
            fused_linear<0, 1><<<nodeBlocks, 256, 0, stream>>>(lin, Wm, bm, P, N);

        if (use_csr) {
            // K2: gather-aggregate + mean + exp0/proj/log0, all fused
            csr_aggregate<<<aggBlocks, 256, 0, stream>>>(P, rowptr, csr, Q, N);
        } else {
            float* cnt = (float*)rowptr;   // reuse
            hipMemsetAsync(Q,   0, (size_t)N * DD * sizeof(float), stream);
            hipMemsetAsync(cnt, 0, (size_t)N * sizeof(float),      stream);
            edge_scatter<<<(E + 3) / 4, 256, 0, stream>>>(P, src, dst, Q, cnt, E);
            finalize_agg<<<nodeBlocks, 256, 0, stream>>>(Q, cnt, N);
        }

        // K3: update linear; last layer emits the actual manifold point
        if (l == L - 1)
            fused_linear<0, 0><<<nodeBlocks, 256, 0, stream>>>(Q, Wu, bu, P, N);
        else
            fused_linear<0, 1><<<nodeBlocks, 256, 0, stream>>>(Q, Wu, bu, P, N);
    }

    if (L % 2 == 1)
        hipMemcpyAsync(d_out, bufA, (size_t)N * DD * sizeof(float),
                       hipMemcpyDeviceToDevice, stream);
}

// Round 3
// 413.205 us; speedup vs baseline: 4.0328x; 1.2011x over previous
//
#include <hip/hip_runtime.h>
#include <math.h>

#define EPSF 1e-5f
#define MAXN 0.95f
#define DD 128

typedef unsigned short u16;
typedef __attribute__((ext_vector_type(8))) __bf16 bf16x8;
typedef __attribute__((ext_vector_type(4))) float f32x4;
typedef __attribute__((ext_vector_type(8))) unsigned short u16x8;

// fp32 -> bf16 (RNE) and back
__device__ __forceinline__ u16 f2bf(float f) {
    unsigned u = __float_as_uint(f);
    return (u16)((u + 0x7FFFu + ((u >> 16) & 1u)) >> 16);
}
__device__ __forceinline__ float bf2f(u16 b) {
    return __uint_as_float(((unsigned)b) << 16);
}

// exp0 -> proj -> (optional log0) collapses to one scalar factor of the row,
// a function of the row norm only.
__device__ __forceinline__ float chain_scale(float nrm, bool log_out) {
    float nc  = fmaxf(nrm, EPSF);
    float f   = tanhf(nc) / nc;          // exp0 factor
    float wn  = f * nrm;                 // ||w|| after exp0
    float p   = (wn > MAXN) ? (MAXN / fmaxf(wn, EPSF)) : 1.f;  // proj
    float s   = f * p;
    if (log_out) {
        float n2  = wn * p;
        float n2c = fmaxf(n2, EPSF);
        float arg = fminf(n2c, 1.f - EPSF);
        s *= atanhf(arg) / n2c;          // log0 factor
    }
    return s;
}

// ---- prep: split weights into bf16 hi/lo planes (once per call) ------------
__global__ __launch_bounds__(256)
void split_w(const float* __restrict__ msgW, const float* __restrict__ updW,
             u16* __restrict__ whi, u16* __restrict__ wlo, int L)
{
    int gid = blockIdx.x * 256 + threadIdx.x;
    int total = L * 2 * DD * DD;
    if (gid >= total) return;
    int mat = gid >> 14;              // /(DD*DD)
    int elem = gid & (DD * DD - 1);
    int l = mat >> 1, tpe = mat & 1;
    float f = (tpe ? updW : msgW)[(size_t)l * DD * DD + elem];
    u16 hb = f2bf(f);
    whi[gid] = hb;
    wlo[gid] = f2bf(f - bf2f(hb));
}

// ---- prep: tangent-ify input x (log0) and split to bf16 hi/lo --------------
__global__ __launch_bounds__(256)
void log0_split(const float* __restrict__ x, u16* __restrict__ hi,
                u16* __restrict__ lo, int N)
{
    int n = blockIdx.x * 64 + (threadIdx.x >> 2);
    int q = threadIdx.x & 3;
    if (n >= N) return;
    const float4* xr = (const float4*)(x + (size_t)n * DD + q * 32);
    float v[32]; float ss = 0.f;
    #pragma unroll
    for (int i = 0; i < 8; ++i) {
        float4 t = xr[i];
        v[i*4+0] = t.x; v[i*4+1] = t.y; v[i*4+2] = t.z; v[i*4+3] = t.w;
        ss += t.x*t.x + t.y*t.y + t.z*t.z + t.w*t.w;
    }
    ss += __shfl_xor(ss, 1); ss += __shfl_xor(ss, 2);
    float nc = fmaxf(sqrtf(ss), EPSF);
    float sc = atanhf(fminf(nc, 1.f - EPSF)) / nc;
    u16* hp = hi + (size_t)n * DD + q * 32;
    u16* lp = lo + (size_t)n * DD + q * 32;
    #pragma unroll
    for (int g = 0; g < 4; ++g) {
        u16x8 h8, l8;
        #pragma unroll
        for (int e = 0; e < 8; ++e) {
            float t = v[g*8 + e] * sc;
            u16 hb = f2bf(t);
            h8[e] = hb;
            l8[e] = f2bf(t - bf2f(hb));
        }
        *(u16x8*)(hp + g*8) = h8;
        *(u16x8*)(lp + g*8) = l8;
    }
}

// ---- MFMA linear: out = chain( v @ W^T + b ), v given as bf16 hi/lo --------
// 3-term split product: vh*Wh + vl*Wh + vh*Wl  (~fp32 accuracy).
// Block = 4 waves, 64-node tile; wave w owns output cols [w*32, w*32+32).
// W fragments live in registers; A fragments loaded straight from global.
template<int LOG_OUT, int FP32_OUT>
__global__ __launch_bounds__(256)
void mfma_linear(const u16* __restrict__ vhi, const u16* __restrict__ vlo,
                 const u16* __restrict__ whi, const u16* __restrict__ wlo,
                 const float* __restrict__ bias,
                 u16* __restrict__ ohi, u16* __restrict__ olo,
                 float* __restrict__ ofp, int N)
{
    __shared__ float sred[4][64];
    const int tid  = threadIdx.x;
    const int w    = tid >> 6;
    const int lane = tid & 63;
    const int l15  = lane & 15, lk = lane >> 4;
    const int base = blockIdx.x * 64;

    // B-operand frags (lane&15 = output col j, 8 consecutive k):
    bf16x8 wh[2][4], wl[2][4];
    #pragma unroll
    for (int nt = 0; nt < 2; ++nt) {
        const int j = w * 32 + nt * 16 + l15;
        #pragma unroll
        for (int kt = 0; kt < 4; ++kt) {
            const int off = j * DD + kt * 32 + lk * 8;
            wh[nt][kt] = *(const bf16x8*)(whi + off);
            wl[nt][kt] = *(const bf16x8*)(wlo + off);
        }
    }
    const float bv0 = bias[w * 32 + l15];
    const float bv1 = bias[w * 32 + 16 + l15];

    f32x4 acc[4][2];
    #pragma unroll
    for (int mt = 0; mt < 4; ++mt)
        #pragma unroll
        for (int nt = 0; nt < 2; ++nt)
            acc[mt][nt] = (f32x4){0.f, 0.f, 0.f, 0.f};

    #pragma unroll
    for (int mt = 0; mt < 4; ++mt) {
        int row = base + mt * 16 + l15;
        row = (row < N) ? row : (N - 1);          // clamp pad rows (not stored)
        const size_t ro = (size_t)row * DD + lk * 8;
        bf16x8 ah[4], al[4];
        #pragma unroll
        for (int kt = 0; kt < 4; ++kt) {
            ah[kt] = *(const bf16x8*)(vhi + ro + kt * 32);
            al[kt] = *(const bf16x8*)(vlo + ro + kt * 32);
        }
        #pragma unroll
        for (int kt = 0; kt < 4; ++kt) {
            #pragma unroll
            for (int nt = 0; nt < 2; ++nt) {
                acc[mt][nt] = __builtin_amdgcn_mfma_f32_16x16x32_bf16(
                    ah[kt], wh[nt][kt], acc[mt][nt], 0, 0, 0);
                acc[mt][nt] = __builtin_amdgcn_mfma_f32_16x16x32_bf16(
                    al[kt], wh[nt][kt], acc[mt][nt], 0, 0, 0);
                acc[mt][nt] = __builtin_amdgcn_mfma_f32_16x16x32_bf16(
                    ah[kt], wl[nt][kt], acc[mt][nt], 0, 0, 0);
            }
        }
    }

    // epilogue: bias, per-row norm across the 4 waves' col slices, scale, store
    float y[4][2][4];
    #pragma unroll
    for (int mt = 0; mt < 4; ++mt) {
        #pragma unroll
        for (int r = 0; r < 4; ++r) {
            y[mt][0][r] = acc[mt][0][r] + bv0;
            y[mt][1][r] = acc[mt][1][r] + bv1;
            float part = y[mt][0][r]*y[mt][0][r] + y[mt][1][r]*y[mt][1][r];
            part += __shfl_xor(part, 1);
            part += __shfl_xor(part, 2);
            part += __shfl_xor(part, 4);
            part += __shfl_xor(part, 8);
            if (l15 == 0) sred[w][mt*16 + lk*4 + r] = part;
        }
    }
    __syncthreads();
    #pragma unroll
    for (int mt = 0; mt < 4; ++mt) {
        #pragma unroll
        for (int r = 0; r < 4; ++r) {
            const int rloc = mt*16 + lk*4 + r;
            float ss = sred[0][rloc] + sred[1][rloc] + sred[2][rloc] + sred[3][rloc];
            float s = chain_scale(sqrtf(ss), LOG_OUT != 0);
            const int rg = base + rloc;
            if (rg < N) {
                #pragma unroll
                for (int nt = 0; nt < 2; ++nt) {
                    float z = y[mt][nt][r] * s;
                    const size_t o = (size_t)rg * DD + w*32 + nt*16 + l15;
                    if (FP32_OUT) {
                        ofp[o] = z;
                    } else {
                        u16 hb = f2bf(z);
                        ohi[o] = hb;
                        olo[o] = f2bf(z - bf2f(hb));
                    }
                }
            }
        }
    }
}

// ---------------- CSR build (edge list is layer-invariant) -------------------
__global__ __launch_bounds__(256)
void degree_k(const int* __restrict__ dst, int* __restrict__ deg, int E)
{
    int e = blockIdx.x * 256 + threadIdx.x;
    if (e < E) atomicAdd(&deg[dst[e]], 1);
}

// Single-block exclusive scan, 4 elems/thread (deg zero-padded to 4096*k).
__global__ __launch_bounds__(1024)
void scan_rowptr(const int* __restrict__ deg, int* __restrict__ rowptr, int N)
{
    __shared__ int wsum[16];
    const int t = threadIdx.x, wv = t >> 6, ln = t & 63;
    int carry = 0;
    const int nch = (N + 4095) / 4096;
    for (int c = 0; c < nch; ++c) {
        const int i = c * 4096 + t * 4;
        int4 d = *(const int4*)(deg + i);
        int e1 = d.x, e2 = e1 + d.y, e3 = e2 + d.z, tot = e3 + d.w;
        int sc = tot;
        #pragma unroll
        for (int off = 1; off < 64; off <<= 1) {
            int u = __shfl_up(sc, off);
            if (ln >= off) sc += u;
        }
        if (ln == 63) wsum[wv] = sc;
        __syncthreads();
        if (wv == 0 && ln < 16) {
            int s2 = wsum[ln];
            #pragma unroll
            for (int off = 1; off < 16; off <<= 1) {
                int u = __shfl_up(s2, off);
                if (ln >= off) s2 += u;
            }
            wsum[ln] = s2;
        }
        __syncthreads();
        const int off0 = carry + ((wv > 0) ? wsum[wv - 1] : 0) + (sc - tot);
        if (i + 3 < N) {
            *(int4*)(rowptr + i) = make_int4(off0, off0 + e1, off0 + e2, off0 + e3);
        } else {
            if (i     < N) rowptr[i]     = off0;
            if (i + 1 < N) rowptr[i + 1] = off0 + e1;
            if (i + 2 < N) rowptr[i + 2] = off0 + e2;
        }
        carry += wsum[15];
        __syncthreads();
    }
    if (t == 0) rowptr[N] = carry;
}

__global__ __launch_bounds__(256)
void fill_csr(const int* __restrict__ src, const int* __restrict__ dst,
              const int* __restrict__ rowptr, int* __restrict__ fill,
              int* __restrict__ csr, int E)
{
    int e = blockIdx.x * 256 + threadIdx.x;
    if (e >= E) return;
    int d = dst[e];
    int pos = rowptr[d] + atomicAdd(&fill[d], 1);
    csr[pos] = src[e];
}

// ---- gather-aggregate (reads hi plane only), fused mean+exp0/proj/log0 -----
__global__ __launch_bounds__(256)
void csr_aggregate(const u16* __restrict__ ghi, const int* __restrict__ rowptr,
                   const int* __restrict__ csr, u16* __restrict__ ohi,
                   u16* __restrict__ olo, int N)
{
    int w = blockIdx.x * 4 + (threadIdx.x >> 6);
    if (w >= N) return;
    const int lane = threadIdx.x & 63;
    const int beg = rowptr[w], end = rowptr[w + 1];
    float ax = 0.f, ay = 0.f;
    for (int b = beg; b < end; b += 64) {
        int cnt = min(end - b, 64);
        int myidx = (lane < cnt) ? csr[b + lane] : 0;  // one coalesced load
        for (int j = 0; j < cnt; ++j) {
            int s = __shfl(myidx, j);
            unsigned u = *(const unsigned*)(ghi + (size_t)s * DD + lane * 2);
            ax += __uint_as_float(u << 16);
            ay += __uint_as_float(u & 0xffff0000u);
        }
    }
    float inv = 1.f / (float)max(end - beg, 1);
    ax *= inv; ay *= inv;
    float ss = ax * ax + ay * ay;
    ss += __shfl_xor(ss, 1);  ss += __shfl_xor(ss, 2);
    ss += __shfl_xor(ss, 4);  ss += __shfl_xor(ss, 8);
    ss += __shfl_xor(ss, 16); ss += __shfl_xor(ss, 32);
    float s = chain_scale(sqrtf(ss), true);
    float zx = ax * s, zy = ay * s;
    u16 hx = f2bf(zx), hy = f2bf(zy);
    *(unsigned*)(ohi + (size_t)w * DD + lane * 2) =
        (unsigned)hx | ((unsigned)hy << 16);
    u16 lx = f2bf(zx - bf2f(hx)), ly = f2bf(zy - bf2f(hy));
    *(unsigned*)(olo + (size_t)w * DD + lane * 2) =
        (unsigned)lx | ((unsigned)ly << 16);
}

extern "C" void kernel_launch(void* const* d_in, const int* in_sizes, int n_in,
                              void* d_out, int out_size, void* d_ws, size_t ws_size,
                              hipStream_t stream)
{
    const float* x     = (const float*)d_in[0];
    const int*   ei    = (const int*)d_in[1];
    const float* msg_W = (const float*)d_in[2];
    const float* msg_b = (const float*)d_in[3];
    const float* upd_W = (const float*)d_in[4];
    const float* upd_b = (const float*)d_in[5];

    const int N = in_sizes[0] / DD;
    const int E = in_sizes[1] / 2;
    const int L = in_sizes[2] / (DD * DD);

    const int* src = ei;
    const int* dst = ei + E;

    // ws layout: A-set hi/lo | W hi | W lo | deg(padded) | rowptr | csr
    u16* Ahi  = (u16*)d_ws;
    u16* Alo  = Ahi + (size_t)N * DD;
    u16* WhiA = Alo + (size_t)N * DD;
    u16* WloA = WhiA + (size_t)2 * L * DD * DD;
    int* deg  = (int*)(WloA + (size_t)2 * L * DD * DD);
    const int degCap = ((N + 4095) / 4096) * 4096;
    int* rowptr = deg + degCap;
    int* csr    = rowptr + (N + 1);

    // B-set lives in d_out (two bf16 planes == out_size fp32 bytes)
    u16* Bhi = (u16*)d_out;
    u16* Blo = Bhi + (size_t)N * DD;

    u16* bufHi[2] = {Ahi, Bhi};
    u16* bufLo[2] = {Alo, Blo};
    // parity chosen so the FINAL linear reads the ws set and writes fp32 d_out
    int cur = (L % 2 == 0) ? 1 : 0;

    const int nodeBlocks = (N + 63) / 64;
    const int aggBlocks  = (N + 3) / 4;
    const int edgeBlocks = (E + 255) / 256;

    split_w<<<(2 * L * DD * DD + 255) / 256, 256, 0, stream>>>(
        msg_W, upd_W, WhiA, WloA, L);
    log0_split<<<nodeBlocks, 256, 0, stream>>>(x, bufHi[cur], bufLo[cur], N);

    hipMemsetAsync(deg, 0, (size_t)degCap * sizeof(int), stream);
    degree_k<<<edgeBlocks, 256, 0, stream>>>(dst, deg, E);
    scan_rowptr<<<1, 1024, 0, stream>>>(deg, rowptr, N);
    hipMemsetAsync(deg, 0, (size_t)N * sizeof(int), stream);
    fill_csr<<<edgeBlocks, 256, 0, stream>>>(src, dst, rowptr, deg, csr, E);

    for (int l = 0; l < L; ++l) {
        const u16* wmh = WhiA + (size_t)(l * 2 + 0) * DD * DD;
        const u16* wml = WloA + (size_t)(l * 2 + 0) * DD * DD;
        const u16* wuh = WhiA + (size_t)(l * 2 + 1) * DD * DD;
        const u16* wul = WloA + (size_t)(l * 2 + 1) * DD * DD;

        // K1: message linear, tangent (log0) output
        mfma_linear<1, 0><<<nodeBlocks, 256, 0, stream>>>(
            bufHi[cur], bufLo[cur], wmh, wml, msg_b + (size_t)l * DD,
            bufHi[cur ^ 1], bufLo[cur ^ 1], nullptr, N);
        cur ^= 1;

        // K2: gather-aggregate + mean + exp0/proj/log0
        csr_aggregate<<<aggBlocks, 256, 0, stream>>>(
            bufHi[cur], rowptr, csr, bufHi[cur ^ 1], bufLo[cur ^ 1], N);
        cur ^= 1;

        // K3: update linear; final layer emits manifold point in fp32
        if (l == L - 1)
            mfma_linear<0, 1><<<nodeBlocks, 256, 0, stream>>>(
                bufHi[cur], bufLo[cur], wuh, wul, upd_b + (size_t)l * DD,
                nullptr, nullptr, (float*)d_out, N);
        else
            mfma_linear<1, 0><<<nodeBlocks, 256, 0, stream>>>(
                bufHi[cur], bufLo[cur], wuh, wul, upd_b + (size_t)l * DD,
                bufHi[cur ^ 1], bufLo[cur ^ 1], nullptr, N);
        cur ^= 1;
    }
}

// Round 4
// 329.135 us; speedup vs baseline: 5.0628x; 1.2554x over previous
//
#include <hip/hip_runtime.h>
#include <math.h>

#define EPSF 1e-5f
#define MAXN 0.95f
#define DD 128

typedef unsigned short u16;
typedef __attribute__((ext_vector_type(8))) __bf16 bf16x8;
typedef __attribute__((ext_vector_type(4))) float f32x4;
typedef __attribute__((ext_vector_type(8))) unsigned short u16x8;

// fp32 -> bf16 (RNE) and back
__device__ __forceinline__ u16 f2bf(float f) {
    unsigned u = __float_as_uint(f);
    return (u16)((u + 0x7FFFu + ((u >> 16) & 1u)) >> 16);
}
__device__ __forceinline__ float bf2f(u16 b) {
    return __uint_as_float(((unsigned)b) << 16);
}

// exp0 -> proj -> (optional log0) collapses to one scalar factor of the row,
// a function of the row norm only.
__device__ __forceinline__ float chain_scale(float nrm, bool log_out) {
    float nc  = fmaxf(nrm, EPSF);
    float f   = tanhf(nc) / nc;          // exp0 factor
    float wn  = f * nrm;                 // ||w|| after exp0
    float p   = (wn > MAXN) ? (MAXN / fmaxf(wn, EPSF)) : 1.f;  // proj
    float s   = f * p;
    if (log_out) {
        float n2  = wn * p;
        float n2c = fmaxf(n2, EPSF);
        float arg = fminf(n2c, 1.f - EPSF);
        s *= atanhf(arg) / n2c;          // log0 factor
    }
    return s;
}

// ---- prep: split weights into bf16 hi/lo planes (once per call) ------------
__global__ __launch_bounds__(256)
void split_w(const float* __restrict__ msgW, const float* __restrict__ updW,
             u16* __restrict__ whi, u16* __restrict__ wlo, int L)
{
    int gid = blockIdx.x * 256 + threadIdx.x;
    int total = L * 2 * DD * DD;
    if (gid >= total) return;
    int mat = gid >> 14;              // /(DD*DD)
    int elem = gid & (DD * DD - 1);
    int l = mat >> 1, tpe = mat & 1;
    float f = (tpe ? updW : msgW)[(size_t)l * DD * DD + elem];
    u16 hb = f2bf(f);
    whi[gid] = hb;
    wlo[gid] = f2bf(f - bf2f(hb));
}

// ---- prep: tangent-ify input x (log0) and split to bf16 hi/lo --------------
__global__ __launch_bounds__(256)
void log0_split(const float* __restrict__ x, u16* __restrict__ hi,
                u16* __restrict__ lo, int N)
{
    int n = blockIdx.x * 64 + (threadIdx.x >> 2);
    int q = threadIdx.x & 3;
    if (n >= N) return;
    const float4* xr = (const float4*)(x + (size_t)n * DD + q * 32);
    float v[32]; float ss = 0.f;
    #pragma unroll
    for (int i = 0; i < 8; ++i) {
        float4 t = xr[i];
        v[i*4+0] = t.x; v[i*4+1] = t.y; v[i*4+2] = t.z; v[i*4+3] = t.w;
        ss += t.x*t.x + t.y*t.y + t.z*t.z + t.w*t.w;
    }
    ss += __shfl_xor(ss, 1); ss += __shfl_xor(ss, 2);
    float nc = fmaxf(sqrtf(ss), EPSF);
    float sc = atanhf(fminf(nc, 1.f - EPSF)) / nc;
    u16* hp = hi + (size_t)n * DD + q * 32;
    u16* lp = lo + (size_t)n * DD + q * 32;
    #pragma unroll
    for (int g = 0; g < 4; ++g) {
        u16x8 h8, l8;
        #pragma unroll
        for (int e = 0; e < 8; ++e) {
            float t = v[g*8 + e] * sc;
            u16 hb = f2bf(t);
            h8[e] = hb;
            l8[e] = f2bf(t - bf2f(hb));
        }
        *(u16x8*)(hp + g*8) = h8;
        *(u16x8*)(lp + g*8) = l8;
    }
}

// ---- MFMA linear: out = chain( v @ W^T + b ), v given as bf16 hi/lo --------
// 3-term split product: vh*Wh + vl*Wh + vh*Wl  (~fp32 accuracy).
// Block = 4 waves, 64-node tile; wave w owns output cols [w*32, w*32+32).
template<int LOG_OUT, int LO_OUT, int FP32_OUT>
__global__ __launch_bounds__(256)
void mfma_linear(const u16* __restrict__ vhi, const u16* __restrict__ vlo,
                 const u16* __restrict__ whi, const u16* __restrict__ wlo,
                 const float* __restrict__ bias,
                 u16* __restrict__ ohi, u16* __restrict__ olo,
                 float* __restrict__ ofp, int N)
{
    __shared__ float sred[4][64];
    __shared__ float sScale[64];
    __shared__ u16 sHi[FP32_OUT ? 1 : 64][144];
    __shared__ u16 sLo[LO_OUT ? 64 : 1][144];

    const int tid  = threadIdx.x;
    const int w    = tid >> 6;
    const int lane = tid & 63;
    const int l15  = lane & 15, lk = lane >> 4;
    const int base = blockIdx.x * 64;

    // B-operand frags (lane&15 = output col j, 8 consecutive k):
    bf16x8 wh[2][4], wl[2][4];
    #pragma unroll
    for (int nt = 0; nt < 2; ++nt) {
        const int j = w * 32 + nt * 16 + l15;
        #pragma unroll
        for (int kt = 0; kt < 4; ++kt) {
            const int off = j * DD + kt * 32 + lk * 8;
            wh[nt][kt] = *(const bf16x8*)(whi + off);
            wl[nt][kt] = *(const bf16x8*)(wlo + off);
        }
    }
    const float bv0 = bias[w * 32 + l15];
    const float bv1 = bias[w * 32 + 16 + l15];

    f32x4 acc[4][2];
    #pragma unroll
    for (int mt = 0; mt < 4; ++mt)
        #pragma unroll
        for (int nt = 0; nt < 2; ++nt)
            acc[mt][nt] = (f32x4){0.f, 0.f, 0.f, 0.f};

    #pragma unroll
    for (int mt = 0; mt < 4; ++mt) {
        int row = base + mt * 16 + l15;
        row = (row < N) ? row : (N - 1);          // clamp pad rows (not stored)
        const size_t ro = (size_t)row * DD + lk * 8;
        bf16x8 ah[4], al[4];
        #pragma unroll
        for (int kt = 0; kt < 4; ++kt) {
            ah[kt] = *(const bf16x8*)(vhi + ro + kt * 32);
            al[kt] = *(const bf16x8*)(vlo + ro + kt * 32);
        }
        #pragma unroll
        for (int kt = 0; kt < 4; ++kt) {
            #pragma unroll
            for (int nt = 0; nt < 2; ++nt) {
                acc[mt][nt] = __builtin_amdgcn_mfma_f32_16x16x32_bf16(
                    ah[kt], wh[nt][kt], acc[mt][nt], 0, 0, 0);
                acc[mt][nt] = __builtin_amdgcn_mfma_f32_16x16x32_bf16(
                    al[kt], wh[nt][kt], acc[mt][nt], 0, 0, 0);
                acc[mt][nt] = __builtin_amdgcn_mfma_f32_16x16x32_bf16(
                    ah[kt], wl[nt][kt], acc[mt][nt], 0, 0, 0);
            }
        }
    }

    // ---- epilogue: per-row norm (cross-wave), one chain_scale per row ------
    #pragma unroll
    for (int mt = 0; mt < 4; ++mt) {
        #pragma unroll
        for (int r = 0; r < 4; ++r) {
            float y0 = acc[mt][0][r] + bv0;
            float y1 = acc[mt][1][r] + bv1;
            float part = y0 * y0 + y1 * y1;
            part += __shfl_xor(part, 1);
            part += __shfl_xor(part, 2);
            part += __shfl_xor(part, 4);
            part += __shfl_xor(part, 8);
            if (l15 == 0) sred[w][mt*16 + lk*4 + r] = part;
        }
    }
    __syncthreads();
    if (tid < 64) {
        float ss = sred[0][tid] + sred[1][tid] + sred[2][tid] + sred[3][tid];
        sScale[tid] = chain_scale(sqrtf(ss), LOG_OUT != 0);
    }
    __syncthreads();

    #pragma unroll
    for (int mt = 0; mt < 4; ++mt) {
        #pragma unroll
        for (int r = 0; r < 4; ++r) {
            const int rloc = mt*16 + lk*4 + r;
            const float s = sScale[rloc];
            #pragma unroll
            for (int nt = 0; nt < 2; ++nt) {
                float z = (acc[mt][nt][r] + (nt ? bv1 : bv0)) * s;
                const int col = w*32 + nt*16 + l15;
                if (FP32_OUT) {
                    const int rg = base + rloc;
                    if (rg < N) ofp[(size_t)rg * DD + col] = z;
                } else {
                    u16 hb = f2bf(z);
                    sHi[rloc][col] = hb;
                    if (LO_OUT) sLo[rloc][col] = f2bf(z - bf2f(hb));
                }
            }
        }
    }
    if (!FP32_OUT) {
        __syncthreads();
        const int row = tid >> 2, qc = (tid & 3) * 32;
        const int rg = base + row;
        if (rg < N) {
            #pragma unroll
            for (int i = 0; i < 4; ++i)
                *(u16x8*)(ohi + (size_t)rg * DD + qc + i*8) =
                    *(const u16x8*)(&sHi[row][qc + i*8]);
            if (LO_OUT) {
                #pragma unroll
                for (int i = 0; i < 4; ++i)
                    *(u16x8*)(olo + (size_t)rg * DD + qc + i*8) =
                        *(const u16x8*)(&sLo[row][qc + i*8]);
            }
        }
    }
}

// ---------------- CSR build (edge list is layer-invariant) -------------------
__global__ __launch_bounds__(256)
void degree_k(const int* __restrict__ dst, int* __restrict__ deg, int E)
{
    int e = blockIdx.x * 256 + threadIdx.x;
    if (e < E) atomicAdd(&deg[dst[e]], 1);
}

// Single-block exclusive scan, 4 elems/thread (deg zero-padded to 4096*k).
__global__ __launch_bounds__(1024)
void scan_rowptr(const int* __restrict__ deg, int* __restrict__ rowptr, int N)
{
    __shared__ int wsum[16];
    const int t = threadIdx.x, wv = t >> 6, ln = t & 63;
    int carry = 0;
    const int nch = (N + 4095) / 4096;
    for (int c = 0; c < nch; ++c) {
        const int i = c * 4096 + t * 4;
        int4 d = *(const int4*)(deg + i);
        int e1 = d.x, e2 = e1 + d.y, e3 = e2 + d.z, tot = e3 + d.w;
        int sc = tot;
        #pragma unroll
        for (int off = 1; off < 64; off <<= 1) {
            int u = __shfl_up(sc, off);
            if (ln >= off) sc += u;
        }
        if (ln == 63) wsum[wv] = sc;
        __syncthreads();
        if (wv == 0 && ln < 16) {
            int s2 = wsum[ln];
            #pragma unroll
            for (int off = 1; off < 16; off <<= 1) {
                int u = __shfl_up(s2, off);
                if (ln >= off) s2 += u;
            }
            wsum[ln] = s2;
        }
        __syncthreads();
        const int off0 = carry + ((wv > 0) ? wsum[wv - 1] : 0) + (sc - tot);
        if (i + 3 < N) {
            *(int4*)(rowptr + i) = make_int4(off0, off0 + e1, off0 + e2, off0 + e3);
        } else {
            if (i     < N) rowptr[i]     = off0;
            if (i + 1 < N) rowptr[i + 1] = off0 + e1;
            if (i + 2 < N) rowptr[i + 2] = off0 + e2;
        }
        carry += wsum[15];
        __syncthreads();
    }
    if (t == 0) rowptr[N] = carry;
}

__global__ __launch_bounds__(256)
void fill_csr(const int* __restrict__ src, const int* __restrict__ dst,
              const int* __restrict__ rowptr, int* __restrict__ fill,
              int* __restrict__ csr, int E)
{
    int e = blockIdx.x * 256 + threadIdx.x;
    if (e >= E) return;
    int d = dst[e];
    int pos = rowptr[d] + atomicAdd(&fill[d], 1);
    csr[pos] = src[e];
}

// ---- gather-aggregate: 4 edges x 16 lanes x 16B, depth-2 pipeline ----------
// out[n] = log0(proj(exp0( mean_{e in in(n)} g[src(e)] )))
__global__ __launch_bounds__(256)
void csr_aggregate(const u16* __restrict__ ghi, const int* __restrict__ rowptr,
                   const int* __restrict__ csr, u16* __restrict__ ohi,
                   u16* __restrict__ olo, int N)
{
    int node = blockIdx.x * 4 + (threadIdx.x >> 6);
    if (node >= N) return;
    const int lane = threadIdx.x & 63;
    const int eg = lane >> 4, l15 = lane & 15;
    const int beg = rowptr[node], end = rowptr[node + 1];

    float acc[8] = {0.f,0.f,0.f,0.f,0.f,0.f,0.f,0.f};
    for (int b = beg; b < end; b += 64) {
        const int cnt = min(end - b, 64);
        const int myidx = (lane < cnt) ? csr[b + lane] : 0;
        // depth-2 software pipeline over groups of 4 edges
        u16x8 vc;
        {
            const bool act = eg < cnt;
            const int s = __shfl(myidx, act ? eg : 0);
            if (act) vc = *(const u16x8*)(ghi + (size_t)s * DD + l15 * 8);
        }
        for (int j = 0; j < cnt; j += 4) {
            const int en = j + 4 + eg;
            const bool actn = en < cnt;
            const int sn = __shfl(myidx, actn ? en : 0);
            u16x8 vn;
            if (actn) vn = *(const u16x8*)(ghi + (size_t)sn * DD + l15 * 8);
            if (j + eg < cnt) {
                #pragma unroll
                for (int q = 0; q < 8; ++q) acc[q] += bf2f((u16)vc[q]);
            }
            vc = vn;
        }
    }
    // reduce the 4 edge-groups (lanes differing in bits 4,5)
    #pragma unroll
    for (int q = 0; q < 8; ++q) {
        acc[q] += __shfl_xor(acc[q], 16);
        acc[q] += __shfl_xor(acc[q], 32);
    }
    const float inv = 1.f / (float)max(end - beg, 1);
    float ss = 0.f;
    #pragma unroll
    for (int q = 0; q < 8; ++q) { acc[q] *= inv; ss += acc[q] * acc[q]; }
    ss += __shfl_xor(ss, 1); ss += __shfl_xor(ss, 2);
    ss += __shfl_xor(ss, 4); ss += __shfl_xor(ss, 8);
    const float s = chain_scale(sqrtf(ss), true);
    if (eg == 0) {
        u16x8 h8, l8;
        #pragma unroll
        for (int q = 0; q < 8; ++q) {
            float z = acc[q] * s;
            u16 hb = f2bf(z);
            h8[q] = hb;
            l8[q] = f2bf(z - bf2f(hb));
        }
        *(u16x8*)(ohi + (size_t)node * DD + l15 * 8) = h8;
        *(u16x8*)(olo + (size_t)node * DD + l15 * 8) = l8;
    }
}

extern "C" void kernel_launch(void* const* d_in, const int* in_sizes, int n_in,
                              void* d_out, int out_size, void* d_ws, size_t ws_size,
                              hipStream_t stream)
{
    const float* x     = (const float*)d_in[0];
    const int*   ei    = (const int*)d_in[1];
    const float* msg_W = (const float*)d_in[2];
    const float* msg_b = (const float*)d_in[3];
    const float* upd_W = (const float*)d_in[4];
    const float* upd_b = (const float*)d_in[5];

    const int N = in_sizes[0] / DD;
    const int E = in_sizes[1] / 2;
    const int L = in_sizes[2] / (DD * DD);

    const int* src = ei;
    const int* dst = ei + E;

    // ws layout: A-set hi/lo | W hi | W lo | deg(padded) | rowptr | csr
    u16* Ahi  = (u16*)d_ws;
    u16* Alo  = Ahi + (size_t)N * DD;
    u16* WhiA = Alo + (size_t)N * DD;
    u16* WloA = WhiA + (size_t)2 * L * DD * DD;
    int* deg  = (int*)(WloA + (size_t)2 * L * DD * DD);
    const int degCap = ((N + 4095) / 4096) * 4096;
    int* rowptr = deg + degCap;
    int* csr    = rowptr + (N + 1);

    // B-set lives in d_out (two bf16 planes == out_size fp32 bytes)
    u16* Bhi = (u16*)d_out;
    u16* Blo = Bhi + (size_t)N * DD;

    u16* bufHi[2] = {Ahi, Bhi};
    u16* bufLo[2] = {Alo, Blo};
    // parity chosen so the FINAL linear reads the ws set and writes fp32 d_out
    int cur = (L % 2 == 0) ? 1 : 0;

    const int nodeBlocks = (N + 63) / 64;
    const int aggBlocks  = (N + 3) / 4;
    const int edgeBlocks = (E + 255) / 256;

    split_w<<<(2 * L * DD * DD + 255) / 256, 256, 0, stream>>>(
        msg_W, upd_W, WhiA, WloA, L);
    log0_split<<<nodeBlocks, 256, 0, stream>>>(x, bufHi[cur], bufLo[cur], N);

    hipMemsetAsync(deg, 0, (size_t)degCap * sizeof(int), stream);
    degree_k<<<edgeBlocks, 256, 0, stream>>>(dst, deg, E);
    scan_rowptr<<<1, 1024, 0, stream>>>(deg, rowptr, N);
    hipMemsetAsync(deg, 0, (size_t)N * sizeof(int), stream);
    fill_csr<<<edgeBlocks, 256, 0, stream>>>(src, dst, rowptr, deg, csr, E);

    for (int l = 0; l < L; ++l) {
        const u16* wmh = WhiA + (size_t)(l * 2 + 0) * DD * DD;
        const u16* wml = WloA + (size_t)(l * 2 + 0) * DD * DD;
        const u16* wuh = WhiA + (size_t)(l * 2 + 1) * DD * DD;
        const u16* wul = WloA + (size_t)(l * 2 + 1) * DD * DD;

        // K1: message linear, tangent output; lo-plane is dead (agg reads hi)
        mfma_linear<1, 0, 0><<<nodeBlocks, 256, 0, stream>>>(
            bufHi[cur], bufLo[cur], wmh, wml, msg_b + (size_t)l * DD,
            bufHi[cur ^ 1], nullptr, nullptr, N);
        cur ^= 1;

        // K2: gather-aggregate + mean + exp0/proj/log0
        csr_aggregate<<<aggBlocks, 256, 0, stream>>>(
            bufHi[cur], rowptr, csr, bufHi[cur ^ 1], bufLo[cur ^ 1], N);
        cur ^= 1;

        // K3: update linear; final layer emits manifold point in fp32
        if (l == L - 1)
            mfma_linear<0, 0, 1><<<nodeBlocks, 256, 0, stream>>>(
                bufHi[cur], bufLo[cur], wuh, wul, upd_b + (size_t)l * DD,
                nullptr, nullptr, (float*)d_out, N);
        else
            mfma_linear<1, 1, 0><<<nodeBlocks, 256, 0, stream>>>(
                bufHi[cur], bufLo[cur], wuh, wul, upd_b + (size_t)l * DD,
                bufHi[cur ^ 1], bufLo[cur ^ 1], nullptr, N);
        cur ^= 1;
    }
}